// Round 7
// baseline (167.542 us; speedup 1.0000x reference)
//
#include <hip/hip_runtime.h>
#include <cstdint>
#include <cstddef>

#define DEV static __device__ __forceinline__

typedef __attribute__((ext_vector_type(8))) short bf16x8;
typedef __attribute__((ext_vector_type(4))) float f32x4;

// fp32 -> bf16 round-to-nearest-even
DEV uint16_t f2bf(float f) {
  uint32_t u = __builtin_bit_cast(uint32_t, f);
  u += 0x7FFFu + ((u >> 16) & 1u);
  return (uint16_t)(u >> 16);
}

// pack two fp32 into two truncated bf16 in one u32 (lo = a, hi = b)
DEV uint32_t packbf(float a, float b) {
  return (__builtin_bit_cast(uint32_t, a) >> 16) |
         (__builtin_bit_cast(uint32_t, b) & 0xFFFF0000u);
}

// native v_exp_f32 (2^x) — avoid __exp2f name clash with glibc math.h
DEV float fexp2(float x) { return __builtin_amdgcn_exp2f(x); }

// DPP cross-lane (VALU pipe): 0xB1 = quad_perm xor1 (used by RoPE epilogue)
template <int CTRL>
DEV float dppf(float v) {
  return __builtin_bit_cast(
      float, __builtin_amdgcn_update_dpp(0, __builtin_bit_cast(int, v), CTRL, 0xF, 0xF, true));
}

// lane ^ 16 exchange via ds_swizzle (xor-16 within 32-lane halves -> lane^16)
DEV float swz16(float v) {
  return __builtin_bit_cast(
      float, __builtin_amdgcn_ds_swizzle(__builtin_bit_cast(int, v), 0x401F));
}
// arbitrary lane gather (pull from lane idx)
DEV float bperm(int lane_idx, float v) {
  return __builtin_bit_cast(
      float, __builtin_amdgcn_ds_bpermute(lane_idx << 2, __builtin_bit_cast(int, v)));
}

// async global->LDS, 16B per lane; LDS dest is wave-uniform base + lane*16
DEV void load_lds16(const void* g, void* l) {
  auto gp = reinterpret_cast<const uint32_t __attribute__((address_space(1)))*>(
      reinterpret_cast<uintptr_t>(g));
  auto lp = reinterpret_cast<uint32_t __attribute__((address_space(3)))*>(
      reinterpret_cast<uintptr_t>(l));
  __builtin_amdgcn_global_load_lds(gp, lp, 16, 0, 0);
}

// fused fp32->bf16 convert for x + 4 weights, PLUS RoPE cos/sin table build.
__global__ __launch_bounds__(256) void cvt_all(const float* __restrict__ x,
                                               const float* __restrict__ wq,
                                               const float* __restrict__ wk,
                                               const float* __restrict__ wv,
                                               const float* __restrict__ wo,
                                               const int* __restrict__ tokpos,
                                               uint16_t* __restrict__ dst,
                                               float2* __restrict__ rtab) {
  int bx = blockIdx.x;
  if (bx >= 8192) {
    int idx = (bx - 8192) * 256 + threadIdx.x;  // 0..65535
    int s = idx >> 5, f = idx & 31;
    float invf = __expf(-0.28782314f * (float)f);  // 10000^(-2f/64)
    float pos = (float)tokpos[s];
    float sn, cs;
    __sincosf(pos * invf, &sn, &cs);
    rtab[idx] = make_float2(cs, sn);
    return;
  }
  int gi = bx * 1024 + threadIdx.x * 4;
  const float* s;
  int li;
  if (gi < 4194304) {
    s = x; li = gi;
  } else {
    int j = gi - 4194304;
    int r = j >> 20;
    li = j & 1048575;
    s = (r == 0) ? wq : (r == 1) ? wk : (r == 2) ? wv : wo;
  }
  float4 v = *reinterpret_cast<const float4*>(s + li);
  ushort4 o;
  o.x = f2bf(v.x); o.y = f2bf(v.y); o.z = f2bf(v.z); o.w = f2bf(v.w);
  *reinterpret_cast<ushort4*>(dst + gi) = o;
}

// Fused QKV GEMM (R14 structure + R15 XCD swizzle: each XCD owns 4 complete
// A-panels (bm rows) so the 24 bn-blocks sharing a panel hit the same L2).
__global__ __launch_bounds__(512) void gemm_qkv(const uint16_t* __restrict__ A,
                                                const uint16_t* __restrict__ Wqkv,
                                                uint16_t* __restrict__ QK,  // Qb; Kb at +4194304
                                                uint16_t* __restrict__ VTb,
                                                const float2* __restrict__ rtab) {
  __shared__ union {
    struct { uint16_t a[2][128 * 64]; uint16_t b[2][128 * 64]; } st;  // 64 KiB dbuf
    uint16_t t[128 * 128];                                            // epilogue transpose
  } sm;

  const int tid = threadIdx.x;
  const int lane = tid & 63, w = tid >> 6;  // w = 0..7
  const int q = lane >> 4, l16 = lane & 15;
  const int wm = w >> 1, wn = w & 1;        // 4 x 2 wave grid

  // XCD-aware remap (nwg = 768 = 8*96): round-robin orig -> contiguous logical
  const int orig = blockIdx.y * 24 + blockIdx.x;
  const int logical = (orig & 7) * 96 + (orig >> 3);
  const int bm = logical / 24, bn = logical % 24;
  const int wsel = bn >> 3;

  const f32x4 z4 = {0.f, 0.f, 0.f, 0.f};
  f32x4 acc[2][4];
#pragma unroll
  for (int i = 0; i < 2; ++i)
#pragma unroll
    for (int j = 0; j < 4; ++j) acc[i][j] = z4;

  const int srow = tid >> 3, sslot = tid & 7;  // srow 0..63
  const uint16_t* Ab = A + (size_t)bm * 128 * 1024;
  const uint16_t* Bb = Wqkv + (size_t)bn * 128 * 1024;

  auto stage = [&](int buf, int k0) {
#pragma unroll
    for (int is = 0; is < 2; ++is) {  // 2 rounds x 64 rows (8 rows/wave)
      int row = is * 64 + srow;
      int gch = sslot ^ (row & 7);
      char* la = (char*)sm.st.a[buf] + (is * 64 + w * 8) * 128;
      char* lb = (char*)sm.st.b[buf] + (is * 64 + w * 8) * 128;
      load_lds16(Ab + (size_t)row * 1024 + k0 + gch * 8, la);
      load_lds16(Bb + (size_t)row * 1024 + k0 + gch * 8, lb);
    }
  };

  stage(0, 0);
  for (int t = 0; t < 16; ++t) {
    const int cur = t & 1;
    __syncthreads();  // drains own prefetch (vmcnt 0) + wave sync
    if (t + 1 < 16) stage(cur ^ 1, (t + 1) * 64);  // flies during body
#pragma unroll
    for (int ks = 0; ks < 2; ++ks) {
      bf16x8 af[2], bfr[4];
#pragma unroll
      for (int i = 0; i < 2; ++i) {
        int ra = wm * 32 + i * 16 + l16;
        af[i] = *reinterpret_cast<const bf16x8*>(sm.st.a[cur] + ra * 64 +
                                                 (((ks * 4 + q) ^ (ra & 7)) * 8));
      }
#pragma unroll
      for (int j = 0; j < 4; ++j) {
        int rb = wn * 64 + j * 16 + l16;
        bfr[j] = *reinterpret_cast<const bf16x8*>(sm.st.b[cur] + rb * 64 +
                                                  (((ks * 4 + q) ^ (rb & 7)) * 8));
      }
#pragma unroll
      for (int i = 0; i < 2; ++i)
#pragma unroll
        for (int j = 0; j < 4; ++j)
          acc[i][j] =
              __builtin_amdgcn_mfma_f32_16x16x32_bf16(af[i], bfr[j], acc[i][j], 0, 0, 0);
    }
  }

  // C/D layout: col = lane&15, row = quad*4 + reg  [m89/m91 verified]
  if (wsel < 2) {
    uint16_t* O = QK + (size_t)wsel * 4194304;
    const float scq = (wsel == 0) ? 0.18033688f : 1.0f;  // (1/8)*log2(e) into Q
#pragma unroll
    for (int j = 0; j < 4; ++j) {
      int gn = bn * 128 + wn * 64 + j * 16 + l16;
      int cn = gn & 1023;
      int f = (gn & 63) >> 1;
      float sgn = (lane & 1) ? 1.f : -1.f;
#pragma unroll
      for (int i = 0; i < 2; ++i) {
#pragma unroll
        for (int r = 0; r < 4; ++r) {
          int gm = bm * 128 + wm * 32 + i * 16 + q * 4 + r;
          float2 cssn = rtab[(gm & 2047) * 32 + f];
          float v = acc[i][j][r];
          float o = dppf<0xB1>(v);  // pair-exchange (xor lane 1) via DPP
          O[(size_t)gm * 1024 + cn] = f2bf((v * cssn.x + sgn * o * cssn.y) * scq);
        }
      }
    }
  } else {
    // V^T [b,h,d,s]
    const int bnv = bn & 7;
    __syncthreads();  // all waves done reading st before aliasing writes to t
#pragma unroll
    for (int i = 0; i < 2; ++i)
#pragma unroll
      for (int j = 0; j < 4; ++j)
#pragma unroll
        for (int r = 0; r < 4; ++r) {
          int mL = wm * 32 + i * 16 + q * 4 + r;
          int nL = wn * 64 + j * 16 + l16;
          int ch = (mL >> 3) ^ (nL & 15);
          sm.t[nL * 128 + ch * 8 + (mL & 7)] = f2bf(acc[i][j][r]);
        }
    __syncthreads();
    const int b = (bm * 128) >> 11;
    const int sblk = (bm * 128) & 2047;
#pragma unroll
    for (int it = 0; it < 4; ++it) {
      int nL = it * 32 + (tid >> 4);  // tid>>4: 0..31
      int mch = tid & 15;
      int slot = mch ^ (nL & 15);
      bf16x8 vv = *reinterpret_cast<const bf16x8*>(sm.t + nL * 128 + slot * 8);
      int gn = bnv * 128 + nL;
      int h = gn >> 6, d = gn & 63;
      *reinterpret_cast<bf16x8*>(VTb + ((size_t)((b * 16 + h) * 64 + d)) * 2048 + sblk +
                                 mch * 8) = vv;
    }
  }
}

// Output projection (R14 structure + R15 XCD swizzle: 8 bm rows per XCD).
__global__ __launch_bounds__(512) void gemm_out(const uint16_t* __restrict__ A,
                                                const uint16_t* __restrict__ Bw,
                                                float* __restrict__ O) {
  __shared__ uint16_t sa[2][128 * 64];  // 32 KiB
  __shared__ uint16_t sb[2][64 * 64];   // 16 KiB

  const int tid = threadIdx.x;
  const int lane = tid & 63, w = tid >> 6;  // 0..7
  const int q = lane >> 4, l16 = lane & 15;
  const int wm = w >> 1, wn = w & 1;        // 4 x 2 wave grid

  // XCD-aware remap (nwg = 512 = 8*64)
  const int orig = blockIdx.y * 16 + blockIdx.x;
  const int logical = (orig & 7) * 64 + (orig >> 3);
  const int bm = logical / 16, bn = logical % 16;

  const f32x4 z4 = {0.f, 0.f, 0.f, 0.f};
  f32x4 acc[2][2];
#pragma unroll
  for (int i = 0; i < 2; ++i)
#pragma unroll
    for (int j = 0; j < 2; ++j) acc[i][j] = z4;

  const int srow = tid >> 3, sslot = tid & 7;  // srow 0..63
  const uint16_t* Ab = A + (size_t)bm * 128 * 1024;
  const uint16_t* Bb = Bw + (size_t)bn * 64 * 1024;

  auto stage = [&](int buf, int k0) {
#pragma unroll
    for (int is = 0; is < 2; ++is) {  // A: 2 rounds x 64 rows
      int row = is * 64 + srow;
      int gch = sslot ^ (row & 7);
      load_lds16(Ab + (size_t)row * 1024 + k0 + gch * 8,
                 (char*)sa[buf] + (is * 64 + w * 8) * 128);
    }
    {  // B: 1 round x 64 rows
      int row = srow;
      int gch = sslot ^ (row & 7);
      load_lds16(Bb + (size_t)row * 1024 + k0 + gch * 8,
                 (char*)sb[buf] + (w * 8) * 128);
    }
  };

  stage(0, 0);
  for (int t = 0; t < 16; ++t) {
    const int cur = t & 1;
    __syncthreads();
    if (t + 1 < 16) stage(cur ^ 1, (t + 1) * 64);
#pragma unroll
    for (int ks = 0; ks < 2; ++ks) {
      bf16x8 af[2], bfr[2];
#pragma unroll
      for (int i = 0; i < 2; ++i) {
        int ra = wm * 32 + i * 16 + l16;
        af[i] = *reinterpret_cast<const bf16x8*>(sa[cur] + ra * 64 +
                                                 (((ks * 4 + q) ^ (ra & 7)) * 8));
      }
#pragma unroll
      for (int j = 0; j < 2; ++j) {
        int rb = wn * 32 + j * 16 + l16;
        bfr[j] = *reinterpret_cast<const bf16x8*>(sb[cur] + rb * 64 +
                                                  (((ks * 4 + q) ^ (rb & 7)) * 8));
      }
#pragma unroll
      for (int i = 0; i < 2; ++i)
#pragma unroll
        for (int j = 0; j < 2; ++j)
          acc[i][j] =
              __builtin_amdgcn_mfma_f32_16x16x32_bf16(af[i], bfr[j], acc[i][j], 0, 0, 0);
    }
  }

#pragma unroll
  for (int i = 0; i < 2; ++i)
#pragma unroll
    for (int r = 0; r < 4; ++r) {
      int gm = bm * 128 + wm * 32 + i * 16 + q * 4 + r;
#pragma unroll
      for (int j = 0; j < 2; ++j) {
        int gn = bn * 64 + wn * 32 + j * 16 + l16;
        O[(size_t)gm * 1024 + gn] = acc[i][j][r];
      }
    }
}

// Flash attention v14: MERGED KV LOOP. Block owns q-tiles A=p and B=15-p;
// tile A's KV range (kt 0..p) is a prefix of B's (kt 0..15-p), so one loop
// kt = 0..15-p stages each K/V tile ONCE and feeds both q-tiles (A active
// while kt <= p). vs v13's two passes (17 stagings): staged bytes & barriers
// drop 17 -> 16-p (avg 12.5, -26%); per-kt body doubles when both tiles
// active -> two independent QK->softmax->PV chains give ILP to fill serial-
// chain bubbles. Compute per block stays exactly 17 tile-visits (balanced).
// Swapped QK^T, per-lane softmax, T13 defer-max, T5 setprio, XCD swizzle
// (4 heads/XCD). Q pre-scaled by (1/8)log2e.
// Q,K: [b,s,h,d]; VT: [b,h,d,s]; AO: [b,s,h,d].
__global__ __launch_bounds__(512) void flash_attn(const uint16_t* __restrict__ Q,
                                                  const uint16_t* __restrict__ K,
                                                  const uint16_t* __restrict__ VT,
                                                  uint16_t* __restrict__ AO) {
  __shared__ uint16_t ksm[2][128 * 64];  // 32 KiB (rows=s, 128B/row, 8-chunk swz)
  __shared__ uint16_t vsm[2][64 * 128];  // 32 KiB (rows=d, 256B/row, 16-chunk swz)
  __shared__ uint16_t psm[8][16 * 128];  // 32 KiB per-wave P (16 rows x 256B)

  const int tid = threadIdx.x;
  const int lane = tid & 63, w = tid >> 6;  // w = 0..7
  const int q = lane >> 4, l16 = lane & 15;

  // XCD-aware remap (nwg = 256 = 8*32): XCD k gets heads 4k..4k+3.
  const int orig = blockIdx.y * 8 + blockIdx.x;
  const int logical = (orig & 7) * 32 + (orig >> 3);
  const int p = logical & 7;        // pair index -> q-tiles {p, 15-p}
  const int bh = logical >> 3;
  const int b = bh >> 4, h = bh & 15;

  const size_t baseBS = (size_t)b * 2048 * 1024 + h * 64;
  const size_t baseVT = (size_t)bh * 64 * 2048;
  uint16_t* pw = psm[w];
  const f32x4 z4 = {0.f, 0.f, 0.f, 0.f};

  // stage one 128-seq K tile (128x64) + V^T tile (64x128) into buf
  auto stage = [&](int buf, int kt) {
#pragma unroll
    for (int is = 0; is < 2; ++is) {  // ksm: 2 steps x 64 rows (8 rows/wave)
      int row = is * 64 + (tid >> 3);
      int gch = (tid & 7) ^ (row & 7);
      load_lds16(K + baseBS + (size_t)(kt * 128 + row) * 1024 + gch * 8,
                 (char*)ksm[buf] + (is * 64 + w * 8) * 128);
    }
#pragma unroll
    for (int is = 0; is < 2; ++is) {  // vsm: 2 steps x 32 rows (4 rows/wave)
      int row = is * 32 + (tid >> 4);
      int gch = (tid & 15) ^ (row & 15);
      load_lds16(VT + baseVT + (size_t)row * 2048 + kt * 128 + gch * 8,
                 (char*)vsm[buf] + (is * 32 + w * 4) * 256);
    }
  };

  const int qtA = p, qtB = 15 - p;
  const int nkt = qtB + 1;  // 9..16 (B's range; A's is a prefix)

  // Q fragments for both tiles (B-layout n=lane&15, k=quad*8+j)
  bf16x8 qfA[2], qfB[2];
#pragma unroll
  for (int ks = 0; ks < 2; ++ks) {
    qfA[ks] = *reinterpret_cast<const bf16x8*>(
        Q + baseBS + (size_t)(qtA * 128 + w * 16 + l16) * 1024 + ks * 32 + q * 8);
    qfB[ks] = *reinterpret_cast<const bf16x8*>(
        Q + baseBS + (size_t)(qtB * 128 + w * 16 + l16) * 1024 + ks * 32 + q * 8);
  }

  f32x4 oaA[4], oaB[4];
#pragma unroll
  for (int di = 0; di < 4; ++di) { oaA[di] = z4; oaB[di] = z4; }
  float m2A = -1e30f, liA = 0.f, m2B = -1e30f, liB = 0.f;

  // per-tile body: QK^T (swapped), causal mask on diag, online softmax with
  // defer-max, P->psm (16-slot swizzle, conflict-free), PV accumulate.
  auto tile_body = [&](int cur, const bf16x8 (&qf)[2], f32x4 (&oa)[4],
                       float& m2, float& li, bool diag) {
    // S^T = K Q^T : sc[nj][r] = S[row=l16][col=nj*16+q*4+r] (within tile)
    f32x4 sc[8];
#pragma unroll
    for (int nj = 0; nj < 8; ++nj) sc[nj] = z4;
#pragma unroll
    for (int ks = 0; ks < 2; ++ks) {
      bf16x8 kf[8];
#pragma unroll
      for (int nj = 0; nj < 8; ++nj) {
        int rk = nj * 16 + l16;
        kf[nj] = *reinterpret_cast<const bf16x8*>(ksm[cur] + rk * 64 +
                                                  (((ks * 4 + q) ^ (rk & 7)) * 8));
      }
      __builtin_amdgcn_s_setprio(1);
#pragma unroll
      for (int nj = 0; nj < 8; ++nj)
        sc[nj] =
            __builtin_amdgcn_mfma_f32_16x16x32_bf16(kf[nj], qf[ks], sc[nj], 0, 0, 0);
      __builtin_amdgcn_s_setprio(0);
    }

    if (diag) {  // causal mask (col > row), k-tile aligned with q-tile
#pragma unroll
      for (int nj = 0; nj < 8; ++nj)
#pragma unroll
        for (int r = 0; r < 4; ++r) {
          int col = nj * 16 + q * 4 + r;
          int row = w * 16 + l16;
          if (col > row) sc[nj][r] = -1e30f;
        }
    }

    // per-lane row max over the lane's 32 values, then cross-quad reduce
    f32x4 m4 = sc[0];
#pragma unroll
    for (int nj = 1; nj < 8; ++nj) {
#pragma unroll
      for (int r = 0; r < 4; ++r) m4[r] = fmaxf(m4[r], sc[nj][r]);
    }
    float pmax = fmaxf(fmaxf(m4[0], m4[1]), fmaxf(m4[2], m4[3]));
    pmax = fmaxf(pmax, swz16(pmax));
    pmax = fmaxf(pmax, bperm(lane ^ 32, pmax));

    // T13 defer-max: only rescale when max grew by > 8 (log2 domain)
    if (__any(pmax > m2 + 8.f)) {
      float mn = fmaxf(m2, pmax);
      float al = fexp2(m2 - mn);  // lane-local (row l16)
      m2 = mn;
      li *= al;
      float ar[4];
#pragma unroll
      for (int r = 0; r < 4; ++r)
        ar[r] = bperm((lane & 48) | (q * 4 + r), al);  // alpha of oa-row q*4+r
#pragma unroll
      for (int di = 0; di < 4; ++di)
#pragma unroll
        for (int r = 0; r < 4; ++r) oa[di][r] *= ar[r];
    }

    // P = 2^(S - m): 4 consecutive k per nj -> pack + one ds_write_b64
    {
      uint16_t* pwr = pw + l16 * 128 + (q & 1) * 4;
      const int swz = l16 & 15;
#pragma unroll
      for (int nj = 0; nj < 8; ++nj) {
        float e0 = fexp2(sc[nj][0] - m2);
        float e1 = fexp2(sc[nj][1] - m2);
        float e2 = fexp2(sc[nj][2] - m2);
        float e3 = fexp2(sc[nj][3] - m2);
        li += (e0 + e1) + (e2 + e3);
        uint64_t pk = (uint64_t)packbf(e0, e1) | ((uint64_t)packbf(e2, e3) << 32);
        *reinterpret_cast<uint64_t*>(
            pwr + (((nj * 2 + (q >> 1)) ^ swz) * 8)) = pk;
      }
    }

    // O += P V over K-dim 128 in 4 chunks (same-wave psm RAW; vsm barrier-guarded)
#pragma unroll
    for (int ks = 0; ks < 4; ++ks) {
      bf16x8 pf = *reinterpret_cast<const bf16x8*>(pw + l16 * 128 +
                                                   (((ks * 4 + q) ^ (l16 & 15)) * 8));
      bf16x8 vf[4];
#pragma unroll
      for (int di = 0; di < 4; ++di) {
        int vr = di * 16 + l16;
        vf[di] = *reinterpret_cast<const bf16x8*>(vsm[cur] + vr * 128 +
                                                  (((ks * 4 + q) ^ (vr & 15)) * 8));
      }
      __builtin_amdgcn_s_setprio(1);
#pragma unroll
      for (int di = 0; di < 4; ++di)
        oa[di] =
            __builtin_amdgcn_mfma_f32_16x16x32_bf16(pf, vf[di], oa[di], 0, 0, 0);
      __builtin_amdgcn_s_setprio(0);
    }
  };

  stage(0, 0);

  for (int kt = 0; kt < nkt; ++kt) {
    const int cur = kt & 1;
    __syncthreads();  // tile kt resident (own loads drained) + wave sync
    if (kt + 1 < nkt) stage(cur ^ 1, kt + 1);  // prefetch flies during body

    if (kt <= qtA) tile_body(cur, qfA, oaA, m2A, liA, kt == qtA);
    tile_body(cur, qfB, oaB, m2B, liB, kt == qtB);
  }

  // finalize both tiles: cross-quad li sum, redistribute 1/li, store coalesced
  auto finalize = [&](int qt, const f32x4 (&oa)[4], float li) {
    float lf = li;
    lf += swz16(lf);
    lf += bperm(lane ^ 32, lf);
    float invL = 1.f / lf;
    float inv_r[4];
#pragma unroll
    for (int r = 0; r < 4; ++r)
      inv_r[r] = bperm((lane & 48) | (q * 4 + r), invL);
#pragma unroll
    for (int r = 0; r < 4; ++r) {
      int gm = qt * 128 + w * 16 + q * 4 + r;
#pragma unroll
      for (int di = 0; di < 4; ++di)
        AO[baseBS + (size_t)gm * 1024 + di * 16 + l16] = f2bf(oa[di][r] * inv_r[r]);
    }
  };
  finalize(qtA, oaA, liA);
  finalize(qtB, oaB, liB);
}

extern "C" void kernel_launch(void* const* d_in, const int* in_sizes, int n_in,
                              void* d_out, int out_size, void* d_ws, size_t ws_size,
                              hipStream_t stream) {
  (void)in_sizes; (void)n_in; (void)out_size; (void)ws_size;
  const float* x = (const float*)d_in[0];
  const int* tokpos = (const int*)d_in[1];
  const float* wq = (const float*)d_in[2];
  const float* wk = (const float*)d_in[3];
  const float* wv = (const float*)d_in[4];
  const float* wo = (const float*)d_in[5];
  float* out = (float*)d_out;

  // workspace layout (bf16 elements) — total 48 MiB (no overflow).
  uint16_t* ws = (uint16_t*)d_ws;
  uint16_t* xb = ws;                   // 4096*1024
  uint16_t* wqb = xb + 4194304;        // wq|wk|wv|wo contiguous, 1M each
  uint16_t* wob = wqb + 3145728;
  uint16_t* Qb = wob + 1048576;        // [b,s,h,d]; Kb at +4194304
  uint16_t* VTb = Qb + 8388608;        // [b,h,d,s]
  uint16_t* AOb = VTb + 4194304;       // [b,s,h,d]
  // rtab OVERLAPS the AOb region (512 KiB at its base): built by cvt_all,
  // read by gemm_qkv, dead before flash_attn overwrites all of AOb.
  float2* rtab = (float2*)AOb;

  cvt_all<<<8448, 256, 0, stream>>>(x, wq, wk, wv, wo, tokpos, xb, rtab);

  gemm_qkv<<<dim3(24, 32), 512, 0, stream>>>(xb, wqb, Qb, VTb, rtab);

  flash_attn<<<dim3(8, 32), 512, 0, stream>>>(Qb, Qb + 4194304, VTb, AOb);

  gemm_out<<<dim3(16, 32), 512, 0, stream>>>(AOb, wob, out);
}

// Round 8
// 160.581 us; speedup vs baseline: 1.0433x; 1.0433x over previous
//
#include <hip/hip_runtime.h>
#include <cstdint>
#include <cstddef>

#define DEV static __device__ __forceinline__

typedef __attribute__((ext_vector_type(8))) short bf16x8;
typedef __attribute__((ext_vector_type(4))) float f32x4;

// fp32 -> bf16 round-to-nearest-even
DEV uint16_t f2bf(float f) {
  uint32_t u = __builtin_bit_cast(uint32_t, f);
  u += 0x7FFFu + ((u >> 16) & 1u);
  return (uint16_t)(u >> 16);
}

// pack two fp32 into two truncated bf16 in one u32 (lo = a, hi = b)
DEV uint32_t packbf(float a, float b) {
  return (__builtin_bit_cast(uint32_t, a) >> 16) |
         (__builtin_bit_cast(uint32_t, b) & 0xFFFF0000u);
}

// native v_exp_f32 (2^x) — avoid __exp2f name clash with glibc math.h
DEV float fexp2(float x) { return __builtin_amdgcn_exp2f(x); }

// DPP cross-lane (VALU pipe): 0xB1 = quad_perm xor1 (used by RoPE epilogue)
template <int CTRL>
DEV float dppf(float v) {
  return __builtin_bit_cast(
      float, __builtin_amdgcn_update_dpp(0, __builtin_bit_cast(int, v), CTRL, 0xF, 0xF, true));
}

// lane ^ 16 exchange via ds_swizzle (xor-16 within 32-lane halves -> lane^16)
DEV float swz16(float v) {
  return __builtin_bit_cast(
      float, __builtin_amdgcn_ds_swizzle(__builtin_bit_cast(int, v), 0x401F));
}
// arbitrary lane gather (pull from lane idx)
DEV float bperm(int lane_idx, float v) {
  return __builtin_bit_cast(
      float, __builtin_amdgcn_ds_bpermute(lane_idx << 2, __builtin_bit_cast(int, v)));
}

// async global->LDS, 16B per lane; LDS dest is wave-uniform base + lane*16
DEV void load_lds16(const void* g, void* l) {
  auto gp = reinterpret_cast<const uint32_t __attribute__((address_space(1)))*>(
      reinterpret_cast<uintptr_t>(g));
  auto lp = reinterpret_cast<uint32_t __attribute__((address_space(3)))*>(
      reinterpret_cast<uintptr_t>(l));
  __builtin_amdgcn_global_load_lds(gp, lp, 16, 0, 0);
}

// fused fp32->bf16 convert for x + 4 weights, PLUS RoPE cos/sin table build.
__global__ __launch_bounds__(256) void cvt_all(const float* __restrict__ x,
                                               const float* __restrict__ wq,
                                               const float* __restrict__ wk,
                                               const float* __restrict__ wv,
                                               const float* __restrict__ wo,
                                               const int* __restrict__ tokpos,
                                               uint16_t* __restrict__ dst,
                                               float2* __restrict__ rtab) {
  int bx = blockIdx.x;
  if (bx >= 8192) {
    int idx = (bx - 8192) * 256 + threadIdx.x;  // 0..65535
    int s = idx >> 5, f = idx & 31;
    float invf = __expf(-0.28782314f * (float)f);  // 10000^(-2f/64)
    float pos = (float)tokpos[s];
    float sn, cs;
    __sincosf(pos * invf, &sn, &cs);
    rtab[idx] = make_float2(cs, sn);
    return;
  }
  int gi = bx * 1024 + threadIdx.x * 4;
  const float* s;
  int li;
  if (gi < 4194304) {
    s = x; li = gi;
  } else {
    int j = gi - 4194304;
    int r = j >> 20;
    li = j & 1048575;
    s = (r == 0) ? wq : (r == 1) ? wk : (r == 2) ? wv : wo;
  }
  float4 v = *reinterpret_cast<const float4*>(s + li);
  ushort4 o;
  o.x = f2bf(v.x); o.y = f2bf(v.y); o.z = f2bf(v.z); o.w = f2bf(v.w);
  *reinterpret_cast<ushort4*>(dst + gi) = o;
}

// Fused QKV GEMM (R14 structure + R15 XCD swizzle: each XCD owns 4 complete
// A-panels (bm rows) so the 24 bn-blocks sharing a panel hit the same L2).
__global__ __launch_bounds__(512) void gemm_qkv(const uint16_t* __restrict__ A,
                                                const uint16_t* __restrict__ Wqkv,
                                                uint16_t* __restrict__ QK,  // Qb; Kb at +4194304
                                                uint16_t* __restrict__ VTb,
                                                const float2* __restrict__ rtab) {
  __shared__ union {
    struct { uint16_t a[2][128 * 64]; uint16_t b[2][128 * 64]; } st;  // 64 KiB dbuf
    uint16_t t[128 * 128];                                            // epilogue transpose
  } sm;

  const int tid = threadIdx.x;
  const int lane = tid & 63, w = tid >> 6;  // w = 0..7
  const int q = lane >> 4, l16 = lane & 15;
  const int wm = w >> 1, wn = w & 1;        // 4 x 2 wave grid

  // XCD-aware remap (nwg = 768 = 8*96): round-robin orig -> contiguous logical
  const int orig = blockIdx.y * 24 + blockIdx.x;
  const int logical = (orig & 7) * 96 + (orig >> 3);
  const int bm = logical / 24, bn = logical % 24;
  const int wsel = bn >> 3;

  const f32x4 z4 = {0.f, 0.f, 0.f, 0.f};
  f32x4 acc[2][4];
#pragma unroll
  for (int i = 0; i < 2; ++i)
#pragma unroll
    for (int j = 0; j < 4; ++j) acc[i][j] = z4;

  const int srow = tid >> 3, sslot = tid & 7;  // srow 0..63
  const uint16_t* Ab = A + (size_t)bm * 128 * 1024;
  const uint16_t* Bb = Wqkv + (size_t)bn * 128 * 1024;

  auto stage = [&](int buf, int k0) {
#pragma unroll
    for (int is = 0; is < 2; ++is) {  // 2 rounds x 64 rows (8 rows/wave)
      int row = is * 64 + srow;
      int gch = sslot ^ (row & 7);
      char* la = (char*)sm.st.a[buf] + (is * 64 + w * 8) * 128;
      char* lb = (char*)sm.st.b[buf] + (is * 64 + w * 8) * 128;
      load_lds16(Ab + (size_t)row * 1024 + k0 + gch * 8, la);
      load_lds16(Bb + (size_t)row * 1024 + k0 + gch * 8, lb);
    }
  };

  stage(0, 0);
  for (int t = 0; t < 16; ++t) {
    const int cur = t & 1;
    __syncthreads();  // drains own prefetch (vmcnt 0) + wave sync
    if (t + 1 < 16) stage(cur ^ 1, (t + 1) * 64);  // flies during body
#pragma unroll
    for (int ks = 0; ks < 2; ++ks) {
      bf16x8 af[2], bfr[4];
#pragma unroll
      for (int i = 0; i < 2; ++i) {
        int ra = wm * 32 + i * 16 + l16;
        af[i] = *reinterpret_cast<const bf16x8*>(sm.st.a[cur] + ra * 64 +
                                                 (((ks * 4 + q) ^ (ra & 7)) * 8));
      }
#pragma unroll
      for (int j = 0; j < 4; ++j) {
        int rb = wn * 64 + j * 16 + l16;
        bfr[j] = *reinterpret_cast<const bf16x8*>(sm.st.b[cur] + rb * 64 +
                                                  (((ks * 4 + q) ^ (rb & 7)) * 8));
      }
#pragma unroll
      for (int i = 0; i < 2; ++i)
#pragma unroll
        for (int j = 0; j < 4; ++j)
          acc[i][j] =
              __builtin_amdgcn_mfma_f32_16x16x32_bf16(af[i], bfr[j], acc[i][j], 0, 0, 0);
    }
  }

  // C/D layout: col = lane&15, row = quad*4 + reg  [m89/m91 verified]
  if (wsel < 2) {
    uint16_t* O = QK + (size_t)wsel * 4194304;
    const float scq = (wsel == 0) ? 0.18033688f : 1.0f;  // (1/8)*log2(e) into Q
#pragma unroll
    for (int j = 0; j < 4; ++j) {
      int gn = bn * 128 + wn * 64 + j * 16 + l16;
      int cn = gn & 1023;
      int f = (gn & 63) >> 1;
      float sgn = (lane & 1) ? 1.f : -1.f;
#pragma unroll
      for (int i = 0; i < 2; ++i) {
#pragma unroll
        for (int r = 0; r < 4; ++r) {
          int gm = bm * 128 + wm * 32 + i * 16 + q * 4 + r;
          float2 cssn = rtab[(gm & 2047) * 32 + f];
          float v = acc[i][j][r];
          float o = dppf<0xB1>(v);  // pair-exchange (xor lane 1) via DPP
          O[(size_t)gm * 1024 + cn] = f2bf((v * cssn.x + sgn * o * cssn.y) * scq);
        }
      }
    }
  } else {
    // V^T [b,h,d,s]
    const int bnv = bn & 7;
    __syncthreads();  // all waves done reading st before aliasing writes to t
#pragma unroll
    for (int i = 0; i < 2; ++i)
#pragma unroll
      for (int j = 0; j < 4; ++j)
#pragma unroll
        for (int r = 0; r < 4; ++r) {
          int mL = wm * 32 + i * 16 + q * 4 + r;
          int nL = wn * 64 + j * 16 + l16;
          int ch = (mL >> 3) ^ (nL & 15);
          sm.t[nL * 128 + ch * 8 + (mL & 7)] = f2bf(acc[i][j][r]);
        }
    __syncthreads();
    const int b = (bm * 128) >> 11;
    const int sblk = (bm * 128) & 2047;
#pragma unroll
    for (int it = 0; it < 4; ++it) {
      int nL = it * 32 + (tid >> 4);  // tid>>4: 0..31
      int mch = tid & 15;
      int slot = mch ^ (nL & 15);
      bf16x8 vv = *reinterpret_cast<const bf16x8*>(sm.t + nL * 128 + slot * 8);
      int gn = bnv * 128 + nL;
      int h = gn >> 6, d = gn & 63;
      *reinterpret_cast<bf16x8*>(VTb + ((size_t)((b * 16 + h) * 64 + d)) * 2048 + sblk +
                                 mch * 8) = vv;
    }
  }
}

// Output projection (R14 structure + R15 XCD swizzle: 8 bm rows per XCD).
__global__ __launch_bounds__(512) void gemm_out(const uint16_t* __restrict__ A,
                                                const uint16_t* __restrict__ Bw,
                                                float* __restrict__ O) {
  __shared__ uint16_t sa[2][128 * 64];  // 32 KiB
  __shared__ uint16_t sb[2][64 * 64];   // 16 KiB

  const int tid = threadIdx.x;
  const int lane = tid & 63, w = tid >> 6;  // 0..7
  const int q = lane >> 4, l16 = lane & 15;
  const int wm = w >> 1, wn = w & 1;        // 4 x 2 wave grid

  // XCD-aware remap (nwg = 512 = 8*64)
  const int orig = blockIdx.y * 16 + blockIdx.x;
  const int logical = (orig & 7) * 64 + (orig >> 3);
  const int bm = logical / 16, bn = logical % 16;

  const f32x4 z4 = {0.f, 0.f, 0.f, 0.f};
  f32x4 acc[2][2];
#pragma unroll
  for (int i = 0; i < 2; ++i)
#pragma unroll
    for (int j = 0; j < 2; ++j) acc[i][j] = z4;

  const int srow = tid >> 3, sslot = tid & 7;  // srow 0..63
  const uint16_t* Ab = A + (size_t)bm * 128 * 1024;
  const uint16_t* Bb = Bw + (size_t)bn * 64 * 1024;

  auto stage = [&](int buf, int k0) {
#pragma unroll
    for (int is = 0; is < 2; ++is) {  // A: 2 rounds x 64 rows
      int row = is * 64 + srow;
      int gch = sslot ^ (row & 7);
      load_lds16(Ab + (size_t)row * 1024 + k0 + gch * 8,
                 (char*)sa[buf] + (is * 64 + w * 8) * 128);
    }
    {  // B: 1 round x 64 rows
      int row = srow;
      int gch = sslot ^ (row & 7);
      load_lds16(Bb + (size_t)row * 1024 + k0 + gch * 8,
                 (char*)sb[buf] + (w * 8) * 128);
    }
  };

  stage(0, 0);
  for (int t = 0; t < 16; ++t) {
    const int cur = t & 1;
    __syncthreads();
    if (t + 1 < 16) stage(cur ^ 1, (t + 1) * 64);
#pragma unroll
    for (int ks = 0; ks < 2; ++ks) {
      bf16x8 af[2], bfr[2];
#pragma unroll
      for (int i = 0; i < 2; ++i) {
        int ra = wm * 32 + i * 16 + l16;
        af[i] = *reinterpret_cast<const bf16x8*>(sa[cur] + ra * 64 +
                                                 (((ks * 4 + q) ^ (ra & 7)) * 8));
      }
#pragma unroll
      for (int j = 0; j < 2; ++j) {
        int rb = wn * 32 + j * 16 + l16;
        bfr[j] = *reinterpret_cast<const bf16x8*>(sb[cur] + rb * 64 +
                                                  (((ks * 4 + q) ^ (rb & 7)) * 8));
      }
#pragma unroll
      for (int i = 0; i < 2; ++i)
#pragma unroll
        for (int j = 0; j < 2; ++j)
          acc[i][j] =
              __builtin_amdgcn_mfma_f32_16x16x32_bf16(af[i], bfr[j], acc[i][j], 0, 0, 0);
    }
  }

#pragma unroll
  for (int i = 0; i < 2; ++i)
#pragma unroll
    for (int r = 0; r < 4; ++r) {
      int gm = bm * 128 + wm * 32 + i * 16 + q * 4 + r;
#pragma unroll
      for (int j = 0; j < 2; ++j) {
        int gn = bn * 64 + wn * 32 + j * 16 + l16;
        O[(size_t)gm * 1024 + gn] = acc[i][j][r];
      }
    }
}

// Flash attention v15 = v13 two-pass structure (balanced pairs {p,15-p},
// conflict-free 16-slot psm) with SINGLE-BUFFERED vsm -> LDS 96 -> 80 KiB
// = 2 blocks/CU x 8 waves = 4 waves/SIMD (was 2). Per-kt schedule:
//   barrier1 (K(kt) resident, vsm free) -> stageV(kt) + stageK(kt+1)
//   -> QK+softmax+P (V flies) -> barrier2 (V drained) -> PV.
// Two barriers/kt, but the co-resident block's waves cover the stalls
// (R0/R3-proven TLP mechanism). Balance & psm swizzle untouched (R4 lessons).
// Swapped QK^T, per-lane softmax, T13 defer-max, T5 setprio, XCD swizzle
// (4 heads/XCD; co-resident blocks = same head, adjacent p -> shared L2).
// Q pre-scaled by (1/8)log2e. Q,K: [b,s,h,d]; VT: [b,h,d,s]; AO: [b,s,h,d].
__global__ __launch_bounds__(512) void flash_attn(const uint16_t* __restrict__ Q,
                                                  const uint16_t* __restrict__ K,
                                                  const uint16_t* __restrict__ VT,
                                                  uint16_t* __restrict__ AO) {
  __shared__ uint16_t ksm[2][128 * 64];  // 32 KiB (rows=s, 128B/row, 8-chunk swz)
  __shared__ uint16_t vsm[64 * 128];     // 16 KiB single buf (rows=d, 16-chunk swz)
  __shared__ uint16_t psm[8][16 * 128];  // 32 KiB per-wave P (16 rows x 256B)

  const int tid = threadIdx.x;
  const int lane = tid & 63, w = tid >> 6;  // w = 0..7
  const int q = lane >> 4, l16 = lane & 15;

  // XCD-aware remap (nwg = 256 = 8*32): XCD k gets heads 4k..4k+3.
  const int orig = blockIdx.y * 8 + blockIdx.x;
  const int logical = (orig & 7) * 32 + (orig >> 3);
  const int p = logical & 7;        // pair index -> q-tiles {p, 15-p}
  const int bh = logical >> 3;
  const int b = bh >> 4, h = bh & 15;

  const size_t baseBS = (size_t)b * 2048 * 1024 + h * 64;
  const size_t baseVT = (size_t)bh * 64 * 2048;
  uint16_t* pw = psm[w];
  const f32x4 z4 = {0.f, 0.f, 0.f, 0.f};

  auto stageK = [&](int buf, int kt) {
#pragma unroll
    for (int is = 0; is < 2; ++is) {  // 2 steps x 64 rows (8 rows/wave)
      int row = is * 64 + (tid >> 3);
      int gch = (tid & 7) ^ (row & 7);
      load_lds16(K + baseBS + (size_t)(kt * 128 + row) * 1024 + gch * 8,
                 (char*)ksm[buf] + (is * 64 + w * 8) * 128);
    }
  };
  auto stageV = [&](int kt) {
#pragma unroll
    for (int is = 0; is < 2; ++is) {  // 2 steps x 32 rows (4 rows/wave)
      int row = is * 32 + (tid >> 4);
      int gch = (tid & 15) ^ (row & 15);
      load_lds16(VT + baseVT + (size_t)row * 2048 + kt * 128 + gch * 8,
                 (char*)vsm + (is * 32 + w * 4) * 256);
    }
  };

  for (int t = 0; t < 2; ++t) {
    const int qt = t ? (15 - p) : p;       // 128-row q-tile index
    const int r0 = qt * 128 + w * 16;      // wave's first q-row
    const int nkt = qt + 1;                // 128-col k-tiles up to diagonal

    // Q fragments (B-layout n=lane&15, k=quad*8+j); Q pre-scaled by (1/8)log2e
    bf16x8 qf[2];
#pragma unroll
    for (int ks = 0; ks < 2; ++ks)
      qf[ks] = *reinterpret_cast<const bf16x8*>(
          Q + baseBS + (size_t)(r0 + l16) * 1024 + ks * 32 + q * 8);

    f32x4 oa[4];
#pragma unroll
    for (int di = 0; di < 4; ++di) oa[di] = z4;
    float m2 = -1e30f, li = 0.f;  // per-lane: running max / denom of q-row l16

    __syncthreads();  // protect ksm[0]/vsm from previous t's readers
    stageK(0, 0);

    for (int kt = 0; kt < nkt; ++kt) {
      const int cur = kt & 1;
      __syncthreads();  // K(kt) resident; vsm free (PV(kt-1) done by all)
      stageV(kt);                               // flies during QK+softmax
      if (kt + 1 < nkt) stageK(cur ^ 1, kt + 1);  // flies during QK+softmax

      // S^T = K Q^T : sc[nj][r] = S[row=l16][col=kt*128+nj*16+q*4+r]
      f32x4 sc[8];
#pragma unroll
      for (int nj = 0; nj < 8; ++nj) sc[nj] = z4;
#pragma unroll
      for (int ks = 0; ks < 2; ++ks) {
        bf16x8 kf[8];
#pragma unroll
        for (int nj = 0; nj < 8; ++nj) {
          int rk = nj * 16 + l16;
          kf[nj] = *reinterpret_cast<const bf16x8*>(ksm[cur] + rk * 64 +
                                                    (((ks * 4 + q) ^ (rk & 7)) * 8));
        }
        __builtin_amdgcn_s_setprio(1);
#pragma unroll
        for (int nj = 0; nj < 8; ++nj)
          sc[nj] =
              __builtin_amdgcn_mfma_f32_16x16x32_bf16(kf[nj], qf[ks], sc[nj], 0, 0, 0);
        __builtin_amdgcn_s_setprio(0);
      }

      if (kt == nkt - 1) {  // diagonal tile: causal mask (col > row)
#pragma unroll
        for (int nj = 0; nj < 8; ++nj)
#pragma unroll
          for (int r = 0; r < 4; ++r) {
            int col = nj * 16 + q * 4 + r;   // within tile; tile == qt
            int row = w * 16 + l16;          // within tile
            if (col > row) sc[nj][r] = -1e30f;
          }
      }

      // per-lane row max over the lane's 32 values, then cross-quad reduce
      f32x4 m4 = sc[0];
#pragma unroll
      for (int nj = 1; nj < 8; ++nj) {
#pragma unroll
        for (int r = 0; r < 4; ++r) m4[r] = fmaxf(m4[r], sc[nj][r]);
      }
      float pmax = fmaxf(fmaxf(m4[0], m4[1]), fmaxf(m4[2], m4[3]));
      pmax = fmaxf(pmax, swz16(pmax));
      pmax = fmaxf(pmax, bperm(lane ^ 32, pmax));

      // T13 defer-max: only rescale when max grew by > 8 (log2 domain)
      if (__any(pmax > m2 + 8.f)) {
        float mn = fmaxf(m2, pmax);
        float al = fexp2(m2 - mn);  // lane-local (row l16)
        m2 = mn;
        li *= al;
        float ar[4];
#pragma unroll
        for (int r = 0; r < 4; ++r)
          ar[r] = bperm((lane & 48) | (q * 4 + r), al);  // alpha of oa-row q*4+r
#pragma unroll
        for (int di = 0; di < 4; ++di)
#pragma unroll
          for (int r = 0; r < 4; ++r) oa[di][r] *= ar[r];
      }

      // P = 2^(S - m): 4 consecutive k per nj -> pack + one ds_write_b64
      {
        uint16_t* pwr = pw + l16 * 128 + (q & 1) * 4;
        const int swz = l16 & 15;
#pragma unroll
        for (int nj = 0; nj < 8; ++nj) {
          float e0 = fexp2(sc[nj][0] - m2);
          float e1 = fexp2(sc[nj][1] - m2);
          float e2 = fexp2(sc[nj][2] - m2);
          float e3 = fexp2(sc[nj][3] - m2);
          li += (e0 + e1) + (e2 + e3);
          uint64_t pk = (uint64_t)packbf(e0, e1) | ((uint64_t)packbf(e2, e3) << 32);
          *reinterpret_cast<uint64_t*>(
              pwr + (((nj * 2 + (q >> 1)) ^ swz) * 8)) = pk;
        }
      }

      __syncthreads();  // V(kt) drained (vmcnt0 before barrier) + wave sync

      // O += P V over K-dim 128 in 4 chunks (same-wave psm RAW)
#pragma unroll
      for (int ks = 0; ks < 4; ++ks) {
        bf16x8 pf = *reinterpret_cast<const bf16x8*>(pw + l16 * 128 +
                                                     (((ks * 4 + q) ^ (l16 & 15)) * 8));
        bf16x8 vf[4];
#pragma unroll
        for (int di = 0; di < 4; ++di) {
          int vr = di * 16 + l16;
          vf[di] = *reinterpret_cast<const bf16x8*>(vsm + vr * 128 +
                                                    (((ks * 4 + q) ^ (vr & 15)) * 8));
        }
        __builtin_amdgcn_s_setprio(1);
#pragma unroll
        for (int di = 0; di < 4; ++di)
          oa[di] =
              __builtin_amdgcn_mfma_f32_16x16x32_bf16(pf, vf[di], oa[di], 0, 0, 0);
        __builtin_amdgcn_s_setprio(0);
      }
    }

    // final: cross-quad li sum, redistribute 1/li to oa rows, store (coalesced)
    float lf = li;
    lf += swz16(lf);
    lf += bperm(lane ^ 32, lf);
    float invL = 1.f / lf;
    float inv_r[4];
#pragma unroll
    for (int r = 0; r < 4; ++r)
      inv_r[r] = bperm((lane & 48) | (q * 4 + r), invL);
#pragma unroll
    for (int r = 0; r < 4; ++r) {
      int gm = r0 + q * 4 + r;
#pragma unroll
      for (int di = 0; di < 4; ++di)
        AO[baseBS + (size_t)gm * 1024 + di * 16 + l16] = f2bf(oa[di][r] * inv_r[r]);
    }
  }
}

extern "C" void kernel_launch(void* const* d_in, const int* in_sizes, int n_in,
                              void* d_out, int out_size, void* d_ws, size_t ws_size,
                              hipStream_t stream) {
  (void)in_sizes; (void)n_in; (void)out_size; (void)ws_size;
  const float* x = (const float*)d_in[0];
  const int* tokpos = (const int*)d_in[1];
  const float* wq = (const float*)d_in[2];
  const float* wk = (const float*)d_in[3];
  const float* wv = (const float*)d_in[4];
  const float* wo = (const float*)d_in[5];
  float* out = (float*)d_out;

  // workspace layout (bf16 elements) — total 48 MiB (no overflow).
  uint16_t* ws = (uint16_t*)d_ws;
  uint16_t* xb = ws;                   // 4096*1024
  uint16_t* wqb = xb + 4194304;        // wq|wk|wv|wo contiguous, 1M each
  uint16_t* wob = wqb + 3145728;
  uint16_t* Qb = wob + 1048576;        // [b,s,h,d]; Kb at +4194304
  uint16_t* VTb = Qb + 8388608;        // [b,h,d,s]
  uint16_t* AOb = VTb + 4194304;       // [b,s,h,d]
  // rtab OVERLAPS the AOb region (512 KiB at its base): built by cvt_all,
  // read by gemm_qkv, dead before flash_attn overwrites all of AOb.
  float2* rtab = (float2*)AOb;

  cvt_all<<<8448, 256, 0, stream>>>(x, wq, wk, wv, wo, tokpos, xb, rtab);

  gemm_qkv<<<dim3(24, 32), 512, 0, stream>>>(xb, wqb, Qb, VTb, rtab);

  flash_attn<<<dim3(8, 32), 512, 0, stream>>>(Qb, Qb + 4194304, VTb, AOb);

  gemm_out<<<dim3(16, 32), 512, 0, stream>>>(AOb, wob, out);
}